// Round 15
// baseline (123.275 us; speedup 1.0000x reference)
//
#include <hip/hip_runtime.h>

#define NPTS 8192
#define BATCH 4
#define BLOCK 256
#define NF 4                    // 32x32 query tiles (A-frags) per wave
#define QPW (NF * 32)           // 128 queries per wave
#define QPB (QPW * 4)           // 512 queries per block
#define QBLOCKS (NPTS / QPB)    // 16
#define SEGS 16
#define SEG_SHIFT 4
#define SEGLEN (NPTS / SEGS)    // 512 targets per segment (16 tiles of 32)

typedef short bf16x8 __attribute__((ext_vector_type(8)));
typedef float f32x16 __attribute__((ext_vector_type(16)));

// fp32 -> bf16 bits (RNE) and back
__device__ inline short f2bf(float v) {
    unsigned u = __float_as_uint(v);
    u += 0x7FFFu + ((u >> 16) & 1u);
    return (short)(u >> 16);
}
__device__ inline float bf2f(short h) {
    return __uint_as_float(((unsigned)(unsigned short)h) << 16);
}

// ---------------------------------------------------------------------------
// MFMA chamfer, 32x32x16 shape (1024 pairs per MFMA; per-CU pipe floor
// ~6.9 us vs 16.5 us for 16x16x32 — R14 measured the 16x16 variant stalling
// at MfmaUtil 21%). d(p,q) = |p|^2 + (|q|^2 - 2 p.q); parenthesized part is
// one MFMA with split-precision K-slots indexed by (g2=lane>>5, j):
//   g2=0, j0-2 : A=-2p_h(xyz)   B=q_h(xyz)
//   g2=0, j3-5 : A=-2p_l(xyz)   B=q_h(xyz)
//   g2=0, j6-7 : A=-2p_h(xy)    B=q_l(xy)
//   g2=1, j0   : A=-2p_h(z)     B=q_l(z)
//   g2=1, j1   : A=1            B=sq_h
//   g2=1, j2   : A=1            B=sq_l     (rest zero)
// A and B use the SAME (g2,j)->k slotting, so the contraction is invariant
// to the ISA's internal k permutation (validated empirically by R14's
// absmax 0.0 on the 16x16 analog). Residual error ~p_l.q_l ~1e-4 << 3.46.
// C/D (m74/m101-verified): col=lane&31 (target n), row=(reg&3)+8*(reg>>2)
// +4*(lane>>5) (query m). Running min3 per acc reg across tile pairs;
// 5-round shfl_xor col-reduction; lane&31==m adds |p|^2 (held locally) and
// atomicMins (mins pre-set 0xFFFFFFFF). Block (0,0,0) zeroes out[0].
// ---------------------------------------------------------------------------
__global__ __launch_bounds__(256, 3) void chamfer_kernel(
    const float* __restrict__ x, const float* __restrict__ y,
    unsigned* __restrict__ mins, float* __restrict__ out) {
    // per target tile (32 pts): 64 bf16x8 entries (g2 in {0,1} x n in [0,32))
    __shared__ bf16x8 ldsB[(SEGLEN / 32) * 64];  // 16 KB

    if (blockIdx.x == 0 && blockIdx.y == 0 && blockIdx.z == 0 && threadIdx.x == 0)
        out[0] = 0.0f;

    const int dir = blockIdx.z;
    const int b = blockIdx.y;
    const int seg = blockIdx.x & (SEGS - 1);
    const int qb = blockIdx.x >> SEG_SHIFT;

    const float* pts = dir ? y : x;  // query set
    const float* oth = dir ? x : y;  // target set

    // ---- stage target segment into LDS (2 targets per thread) ----
    for (int p = threadIdx.x; p < SEGLEN; p += BLOCK) {
        const float* q = oth + ((size_t)b * NPTS + seg * SEGLEN + p) * 3;
        const float qx = q[0], qy = q[1], qz = q[2];
        const float sq = fmaf(qz, qz, fmaf(qy, qy, qx * qx));
        const short qhx = f2bf(qx), qhy = f2bf(qy), qhz = f2bf(qz);
        const short qlx = f2bf(qx - bf2f(qhx));
        const short qly = f2bf(qy - bf2f(qhy));
        const short qlz = f2bf(qz - bf2f(qhz));
        const short sqh = f2bf(sq);
        const short sql = f2bf(sq - bf2f(sqh));
        bf16x8 b0, b1;
        b0[0] = qhx; b0[1] = qhy; b0[2] = qhz;
        b0[3] = qhx; b0[4] = qhy; b0[5] = qhz;
        b0[6] = qlx; b0[7] = qly;
        b1[0] = qlz; b1[1] = sqh; b1[2] = sql;
        b1[3] = 0; b1[4] = 0; b1[5] = 0; b1[6] = 0; b1[7] = 0;
        const int tile = p >> 5, nn = p & 31;
        ldsB[tile * 64 + nn] = b0;
        ldsB[tile * 64 + 32 + nn] = b1;
    }

    // ---- A-frags (queries) ----
    const int lane = threadIdx.x & 63;
    const int wv = threadIdx.x >> 6;        // wave 0..3
    const int n = lane & 31;                // within-tile index (query m / target n)
    const int g2 = lane >> 5;               // k-slot group 0..1
    const int qbase = qb * QPB + wv * QPW;  // this wave's first query

    bf16x8 afrag[NF];
    float sp[NF];
    f32x16 best[NF];
    const short one = f2bf(1.0f);
#pragma unroll
    for (int f = 0; f < NF; ++f) {
        const int qi = qbase + f * 32 + n;
        const float* p = pts + ((size_t)b * NPTS + qi) * 3;
        const float px = p[0], py = p[1], pz = p[2];
        sp[f] = fmaf(pz, pz, fmaf(py, py, px * px));
        const short phx = f2bf(px), phy = f2bf(py), phz = f2bf(pz);
        bf16x8 a;
#pragma unroll
        for (int i = 0; i < 8; ++i) a[i] = 0;
        if (g2 == 0) {
            a[0] = f2bf(-2.0f * bf2f(phx));
            a[1] = f2bf(-2.0f * bf2f(phy));
            a[2] = f2bf(-2.0f * bf2f(phz));
            a[3] = f2bf(-2.0f * (px - bf2f(phx)));
            a[4] = f2bf(-2.0f * (py - bf2f(phy)));
            a[5] = f2bf(-2.0f * (pz - bf2f(phz)));
            a[6] = f2bf(-2.0f * bf2f(phx));
            a[7] = f2bf(-2.0f * bf2f(phy));
        } else {
            a[0] = f2bf(-2.0f * bf2f(phz));
            a[1] = one;
            a[2] = one;
        }
        afrag[f] = a;
#pragma unroll
        for (int r = 0; r < 16; ++r) best[f][r] = 3.0e38f;
    }

    __syncthreads();

    // ---- main loop: 2 target tiles per iteration, NF*2 independent MFMAs ----
    const f32x16 zero16 = {0};
    for (int t = 0; t < SEGLEN / 32; t += 2) {
        const bf16x8 bv0 = ldsB[t * 64 + g2 * 32 + n];
        const bf16x8 bv1 = ldsB[(t + 1) * 64 + g2 * 32 + n];
#pragma unroll
        for (int f = 0; f < NF; ++f) {
            const f32x16 c0 = __builtin_amdgcn_mfma_f32_32x32x16_bf16(
                afrag[f], bv0, zero16, 0, 0, 0);
            const f32x16 c1 = __builtin_amdgcn_mfma_f32_32x32x16_bf16(
                afrag[f], bv1, zero16, 0, 0, 0);
#pragma unroll
            for (int r = 0; r < 16; ++r)
                best[f][r] = fminf(fminf(best[f][r], c0[r]), c1[r]);  // v_min3
        }
    }

    // ---- epilogue: col(n)-reduce per row, add |p|^2, atomicMin ----
    unsigned* om = mins + (size_t)(dir * BATCH + b) * NPTS;
#pragma unroll
    for (int f = 0; f < NF; ++f) {
#pragma unroll
        for (int r = 0; r < 16; ++r) {
            float v = best[f][r];
            v = fminf(v, __shfl_xor(v, 1, 64));
            v = fminf(v, __shfl_xor(v, 2, 64));
            v = fminf(v, __shfl_xor(v, 4, 64));
            v = fminf(v, __shfl_xor(v, 8, 64));
            v = fminf(v, __shfl_xor(v, 16, 64));
            const int m = (r & 3) + 8 * (r >> 2) + 4 * g2;  // query row
            if (n == m) {  // this lane loaded query m -> sp[f] is |p_m|^2
                const float d = fmaxf(sp[f] + v, 0.0f);
                atomicMin(&om[qbase + f * 32 + m], __float_as_uint(d));
            }
        }
    }
}

// ---------------------------------------------------------------------------
// finalize: 64 blocks x 256 threads (R7-R13 proven). Each block sums a 4 KB
// slice of mins (uint4, coalesced), reduces, atomicAdds partial * 1/(B*N)
// into out[0] (zeroed by chamfer block 0). gid 0 adds the regularizer.
// ---------------------------------------------------------------------------
__global__ __launch_bounds__(256) void finalize_kernel(
    const unsigned* __restrict__ mins, const float* __restrict__ R,
    const float* __restrict__ S, const float* __restrict__ t,
    const float* __restrict__ R_gt, const float* __restrict__ S_gt,
    const float* __restrict__ t_gt, float* __restrict__ out) {
    const uint4* m4 = (const uint4*)mins;  // 2*B*N/4 = 16384 uint4s
    const int gid = blockIdx.x * 256 + (int)threadIdx.x;
    const uint4 u = m4[gid];
    float v = (__uint_as_float(u.x) + __uint_as_float(u.y) +
               __uint_as_float(u.z) + __uint_as_float(u.w)) *
              (1.0f / (BATCH * NPTS));

    if (gid == 0) {
        float acc = 0.0f;
        for (int b = 0; b < BATCH; ++b)
            for (int i = 0; i < 3; ++i)
                for (int k = 0; k < 3; ++k) {
                    float s = 0.0f;
                    for (int j = 0; j < 3; ++j)
                        s += R_gt[b * 9 + j * 3 + i] * R[b * 9 + j * 3 + k];
                    s -= (i == k) ? 1.0f : 0.0f;
                    acc += s * s;
                }
        for (int d = 0; d < 3; ++d)  // jnp.diagonal(S, axis1=0, axis2=1)
            for (int a = 0; a < 3; ++a) {
                const float diff = S[d * 9 + d * 3 + a] - S_gt[d * 9 + d * 3 + a];
                acc += diff * diff;
            }
        for (int b = 0; b < BATCH; ++b)
            for (int k = 0; k < 3; ++k) {
                const float diff = t[b * 3 + k] - t_gt[b * 3 + k];
                acc += diff * diff;
            }
        v += acc;
    }

    for (int off = 32; off; off >>= 1) v += __shfl_down(v, off, 64);
    __shared__ float wsum[4];
    const int lane = threadIdx.x & 63;
    const int wave = threadIdx.x >> 6;
    if (lane == 0) wsum[wave] = v;
    __syncthreads();
    if (wave == 0) {
        v = (lane < 4) ? wsum[lane] : 0.0f;
        for (int off = 2; off; off >>= 1) v += __shfl_down(v, off, 64);
        if (lane == 0) atomicAdd(out, v);
    }
}

extern "C" void kernel_launch(void* const* d_in, const int* in_sizes, int n_in,
                              void* d_out, int out_size, void* d_ws, size_t ws_size,
                              hipStream_t stream) {
    const float* x    = (const float*)d_in[0];
    const float* y    = (const float*)d_in[1];
    const float* R    = (const float*)d_in[2];
    const float* S    = (const float*)d_in[3];
    const float* t    = (const float*)d_in[4];
    const float* R_gt = (const float*)d_in[5];
    const float* S_gt = (const float*)d_in[6];
    const float* t_gt = (const float*)d_in[7];
    float* out = (float*)d_out;
    unsigned* mins = (unsigned*)d_ws;  // 2*B*N uints = 256 KiB

    hipMemsetAsync(mins, 0xFF, (size_t)2 * BATCH * NPTS * sizeof(unsigned), stream);

    chamfer_kernel<<<dim3(QBLOCKS * SEGS, BATCH, 2), dim3(BLOCK), 0, stream>>>(
        x, y, mins, out);

    finalize_kernel<<<dim3(2 * BATCH * NPTS / 4 / 256), dim3(BLOCK), 0, stream>>>(
        mins, R, S, t, R_gt, S_gt, t_gt, out);
}

// Round 16
// 106.548 us; speedup vs baseline: 1.1570x; 1.1570x over previous
//
#include <hip/hip_runtime.h>

#define NPTS 8192
#define BATCH 4
#define BLOCK 256
#define NQ 8                   // queries per thread
#define QPB (BLOCK * NQ)       // 2048 queries per block
#define QBLOCKS (NPTS / QPB)   // 4
#define SEGS 64
#define SEG_SHIFT 6
#define SEGLEN (NPTS / SEGS)   // 128 targets per segment

typedef float v2f __attribute__((ext_vector_type(2)));

// ---------------------------------------------------------------------------
// chamfer: grid (QBLOCKS*SEGS, BATCH, 2). Expanded form d = |p|^2+|q|^2-2p.q.
// R9/R13-proven hot loop (43.7-44.0 us, fp32-FMA-datapath-bound; R8/R9 A/B
// falsified instruction-issue and LDS-pipe limits; R14/R15 measured both
// MFMA reformulations slower due to the min-after-MFMA accumulator tax).
// Block (0,0,0) zeroes out[0], replacing the out-memset graph node.
// LDS: tgtA[j]={x0,x1,y0,y1}, tgtB[j]={z0,z1,|q0|^2,|q1|^2} (paired targets)
// -> pairs are VGPR-pair-aligned off ds_read_b128, enabling v_pk_fma_f32.
// Partial mins merged via atomicMin on float bits (distances clamped >= 0,
// so uint order == float order); mins initialized to 0xFFFFFFFF by memset.
// ---------------------------------------------------------------------------
__global__ __launch_bounds__(256) void chamfer_kernel(
    const float* __restrict__ x, const float* __restrict__ y,
    unsigned* __restrict__ mins, float* __restrict__ out) {
    __shared__ float4 tgtA[SEGLEN / 2];
    __shared__ float4 tgtB[SEGLEN / 2];

    if (blockIdx.x == 0 && blockIdx.y == 0 && blockIdx.z == 0 && threadIdx.x == 0)
        out[0] = 0.0f;

    const int dir = blockIdx.z;
    const int b = blockIdx.y;
    const int seg = blockIdx.x & (SEGS - 1);
    const int qb = blockIdx.x >> SEG_SHIFT;

    const float* pts = dir ? y : x;  // query set
    const float* oth = dir ? x : y;  // target set

    // stage one segment: one point per thread (SEGLEN <= BLOCK)
    if (threadIdx.x < SEGLEN) {
        const int p = threadIdx.x;
        const float* q = oth + ((size_t)b * NPTS + seg * SEGLEN + p) * 3;
        const float qx = q[0], qy = q[1], qz = q[2];
        const float sq = fmaf(qz, qz, fmaf(qy, qy, qx * qx));
        float* A = (float*)tgtA;
        float* Bv = (float*)tgtB;
        const int pi = p >> 1, par = p & 1;
        A[pi * 4 + par] = qx;
        A[pi * 4 + 2 + par] = qy;
        Bv[pi * 4 + par] = qz;
        Bv[pi * 4 + 2 + par] = sq;
    }

    // query points -> registers as packed splats (-2*p per component);
    // |p|^2 folded in at the end.
    v2f m2x[NQ], m2y[NQ], m2z[NQ];
    float sp[NQ], best[NQ];
    const int qbase = b * NPTS + qb * QPB + (int)threadIdx.x;
#pragma unroll
    for (int k = 0; k < NQ; ++k) {
        const float* p = pts + (size_t)(qbase + k * BLOCK) * 3;
        const float px = p[0], py = p[1], pz = p[2];
        m2x[k] = (v2f){-2.0f * px, -2.0f * px};
        m2y[k] = (v2f){-2.0f * py, -2.0f * py};
        m2z[k] = (v2f){-2.0f * pz, -2.0f * pz};
        sp[k] = fmaf(pz, pz, fmaf(py, py, px * px));
        best[k] = 3.0e38f;
    }

    __syncthreads();

#pragma unroll 2
    for (int j = 0; j < SEGLEN / 2; ++j) {
        const float4 A = tgtA[j];
        const float4 Bv = tgtB[j];
        const v2f qx2 = {A.x, A.y};
        const v2f qy2 = {A.z, A.w};
        const v2f qz2 = {Bv.x, Bv.y};
        const v2f sq2 = {Bv.z, Bv.w};
#pragma unroll
        for (int k = 0; k < NQ; ++k) {
            // ffp-contract=fast fuses into v_pk_fma_f32
            v2f d = qx2 * m2x[k] + sq2;
            d = qy2 * m2y[k] + d;
            d = qz2 * m2z[k] + d;
            best[k] = fminf(fminf(best[k], d.x), d.y);  // v_min3_f32
        }
    }

    unsigned* om = mins + (size_t)(dir * BATCH + b) * NPTS + qb * QPB + threadIdx.x;
#pragma unroll
    for (int k = 0; k < NQ; ++k) {
        const float d = fmaxf(sp[k] + best[k], 0.0f);  // >=0: uint order == float order
        atomicMin(&om[k * BLOCK], __float_as_uint(d));
    }
}

// ---------------------------------------------------------------------------
// finalize: 64 blocks x 256 threads (R7-R13 proven). Each block sums a
// 4 KB slice of mins (uint4, coalesced), reduces, atomicAdds partial *
// 1/(B*N) into out[0] (zeroed by chamfer block 0). gid 0 adds the
// regularizer term.
// ---------------------------------------------------------------------------
__global__ __launch_bounds__(256) void finalize_kernel(
    const unsigned* __restrict__ mins, const float* __restrict__ R,
    const float* __restrict__ S, const float* __restrict__ t,
    const float* __restrict__ R_gt, const float* __restrict__ S_gt,
    const float* __restrict__ t_gt, float* __restrict__ out) {
    const uint4* m4 = (const uint4*)mins;  // 2*B*N/4 = 16384 uint4s
    const int gid = blockIdx.x * 256 + (int)threadIdx.x;  // 0..16383
    const uint4 u = m4[gid];
    float v = (__uint_as_float(u.x) + __uint_as_float(u.y) +
               __uint_as_float(u.z) + __uint_as_float(u.w)) *
              (1.0f / (BATCH * NPTS));

    if (gid == 0) {
        float acc = 0.0f;
        for (int b = 0; b < BATCH; ++b)
            for (int i = 0; i < 3; ++i)
                for (int k = 0; k < 3; ++k) {
                    float s = 0.0f;
                    for (int j = 0; j < 3; ++j)
                        s += R_gt[b * 9 + j * 3 + i] * R[b * 9 + j * 3 + k];
                    s -= (i == k) ? 1.0f : 0.0f;
                    acc += s * s;
                }
        for (int d = 0; d < 3; ++d)  // jnp.diagonal(S, axis1=0, axis2=1)
            for (int a = 0; a < 3; ++a) {
                const float diff = S[d * 9 + d * 3 + a] - S_gt[d * 9 + d * 3 + a];
                acc += diff * diff;
            }
        for (int b = 0; b < BATCH; ++b)
            for (int k = 0; k < 3; ++k) {
                const float diff = t[b * 3 + k] - t_gt[b * 3 + k];
                acc += diff * diff;
            }
        v += acc;
    }

    // block reduction: 4 waves of 64
    for (int off = 32; off; off >>= 1) v += __shfl_down(v, off, 64);
    __shared__ float wsum[4];
    const int lane = threadIdx.x & 63;
    const int wave = threadIdx.x >> 6;
    if (lane == 0) wsum[wave] = v;
    __syncthreads();
    if (wave == 0) {
        v = (lane < 4) ? wsum[lane] : 0.0f;
        for (int off = 2; off; off >>= 1) v += __shfl_down(v, off, 64);
        if (lane == 0) atomicAdd(out, v);
    }
}

extern "C" void kernel_launch(void* const* d_in, const int* in_sizes, int n_in,
                              void* d_out, int out_size, void* d_ws, size_t ws_size,
                              hipStream_t stream) {
    const float* x    = (const float*)d_in[0];
    const float* y    = (const float*)d_in[1];
    const float* R    = (const float*)d_in[2];
    const float* S    = (const float*)d_in[3];
    const float* t    = (const float*)d_in[4];
    const float* R_gt = (const float*)d_in[5];
    const float* S_gt = (const float*)d_in[6];
    const float* t_gt = (const float*)d_in[7];
    float* out = (float*)d_out;
    unsigned* mins = (unsigned*)d_ws;  // 2*B*N uints = 256 KiB

    // init mins to 0xFFFFFFFF (uint max) for atomicMin
    hipMemsetAsync(mins, 0xFF, (size_t)2 * BATCH * NPTS * sizeof(unsigned), stream);

    chamfer_kernel<<<dim3(QBLOCKS * SEGS, BATCH, 2), dim3(BLOCK), 0, stream>>>(
        x, y, mins, out);

    finalize_kernel<<<dim3(2 * BATCH * NPTS / 4 / 256), dim3(BLOCK), 0, stream>>>(
        mins, R, S, t, R_gt, S_gt, t_gt, out);
}